// Round 2
// baseline (110.199 us; speedup 1.0000x reference)
//
#include <hip/hip_runtime.h>

// TreeCRF inside pass, L=32 channels, perfect binary tree (heap layout).
// parent[i] = em[i] + LSE_j(T[i,j]+left[j]) + LSE_j(T[i,j]+right[j])
//
// R14 = R13 (linear-domain propagation) with:
//  (1) SINGLE-LAUNCH fusion: the K1/K2 kernel boundary is replaced by
//      poison-tolerant per-block done-flags + fine-grained spin-acquire.
//      Stage-2 blocks (0..31) each wait only on their 8 producer blocks, so
//      stage-2 overlaps stage-1 stragglers; block 0 runs the 128->4->1 tail.
//      MAGIC has 4 distinct bytes (no byte-repeated poison fill can forge it)
//      and block 0 clears all flags at kernel end (hidden under the root
//      reduce), so repeated graph replays are safe with or without re-poison.
//  (2) power-of-2 renormalization: per level, scale = 2^-ex (exact bit op,
//      replaces rcp) and M += ex*ln2 (fma, replaces __logf) — only the final
//      level pays a real log to return to the log-domain interface.
//
// Deadlock-safety: only blocks 0..31 spin; >=768 of 1024 blocks are resident
// concurrently (LDS ~11 KB/block) and retiring stage-1 blocks backfill, so
// producers always make progress.

typedef float f32x4 __attribute__((ext_vector_type(4)));
typedef short s16x8 __attribute__((ext_vector_type(8)));
typedef short s16x4 __attribute__((ext_vector_type(4)));

#define CSTR 40   // C row stride in shorts (80 B: 16B-aligned, <=2-way banks)
#define LDS_WAIT() __asm__ volatile("s_waitcnt lgkmcnt(0)" ::: "memory")
#define DONE_MAGIC 0x5A17C0DE
#define LN2F 0.69314718055994531f

__device__ __forceinline__ short f2bf(float f) {
    unsigned u = __builtin_bit_cast(unsigned, f);
    unsigned r = (u + 0x7fffu + ((u >> 16) & 1u)) >> 16;   // RNE to bf16
    return (short)r;
}

__device__ __forceinline__ float max4(float4 v) {
    return fmaxf(fmaxf(v.x, v.y), fmaxf(v.z, v.w));
}

__device__ __forceinline__ void load_afrag(const float* __restrict__ trans,
                                           int row, int kg, s16x8* a)
{
#pragma unroll
    for (int j = 0; j < 8; ++j)
        (*a)[j] = f2bf(__expf(trans[row * 32 + kg * 8 + j]));
}

// Spin until flags[0..n) all hold DONE_MAGIC (lane l polls flags[l], sticky),
// then acquire-fence. Wave-uniform loop; s_sleep keeps issue pressure low.
__device__ __forceinline__ void spin_acquire(int* flags, int lane, int n)
{
    bool got = lane >= n;
    int idx = got ? 0 : lane;
    for (;;) {
        if (!got)
            got = (atomicAdd(&flags[idx], 0) == DONE_MAGIC);
        if (__all((int)got)) break;
        __builtin_amdgcn_s_sleep(2);
    }
    __threadfence();                       // acquire: producers' rows visible
}

// One wave reduces NC0 rows -> one f32 output row (log2(NC0) levels), fully
// autonomously. em node at step s: (inW>>s)-1 + sid*(NC0>>s) + p.
template <int NC0>
__device__ __forceinline__ void wave_reduce(
    int lane, const float* rows, const float* __restrict__ em, int inW,
    int sid, s16x8 a0, s16x8 a1, short* C, float* M, float* outrow)
{
    constexpr int STEPS = (NC0 == 32) ? 5 : 2;
    constexpr int NPH = (NC0 == 32) ? 6 : 2;
    const int ql = lane & 15, kg = lane >> 4;
    const int q0 = lane & 31, h = lane >> 5;

    // stage-0 row loads first
    float4 x0 = {0,0,0,0}, x1 = x0, x2 = x0, x3 = x0;
    if (q0 < NC0) {
        const float4* src = (const float4*)(rows + q0 * 32 + h * 16);
        x0 = src[0]; x1 = src[1]; x2 = src[2]; x3 = src[3];
    }

    // prefetch ALL em rows needed by the phases (independent, in-flight)
    float4 pe0[NPH], pe1[NPH];
    {
        int ph = 0;
#pragma unroll
        for (int s = 1; s <= STEPS; ++s) {
            const int nca = NC0 >> (s - 1);
            const int nstr = (nca >= 16) ? (nca >> 4) : 1;
#pragma unroll
            for (int st = 0; st < nstr; ++st, ++ph) {
                int p = (st * 16 + ql) >> 1;
                size_t node = (size_t)((inW >> s) - 1)
                            + (size_t)sid * (NC0 >> s) + p;
                pe0[ph] = *(const float4*)(em + node * 32 + kg * 4);
                pe1[ph] = *(const float4*)(em + node * 32 + 16 + kg * 4);
            }
        }
    }

    // stage 0: V = exp(x - rowmax) -> C, rowmax -> M. (True-max normalization
    // kept here: inputs are arbitrary log-domain scores.)
    if (q0 < NC0) {
        float mm = fmaxf(fmaxf(max4(x0), max4(x1)),
                         fmaxf(max4(x2), max4(x3)));
        mm = fmaxf(mm, __shfl_xor(mm, 32));       // combine the two halves
        s16x8 w0, w1;
        w0[0] = f2bf(__expf(x0.x - mm)); w0[1] = f2bf(__expf(x0.y - mm));
        w0[2] = f2bf(__expf(x0.z - mm)); w0[3] = f2bf(__expf(x0.w - mm));
        w0[4] = f2bf(__expf(x1.x - mm)); w0[5] = f2bf(__expf(x1.y - mm));
        w0[6] = f2bf(__expf(x1.z - mm)); w0[7] = f2bf(__expf(x1.w - mm));
        w1[0] = f2bf(__expf(x2.x - mm)); w1[1] = f2bf(__expf(x2.y - mm));
        w1[2] = f2bf(__expf(x2.z - mm)); w1[3] = f2bf(__expf(x2.w - mm));
        w1[4] = f2bf(__expf(x3.x - mm)); w1[5] = f2bf(__expf(x3.y - mm));
        w1[6] = f2bf(__expf(x3.z - mm)); w1[7] = f2bf(__expf(x3.w - mm));
        *(s16x8*)(C + q0 * CSTR + h * 16) = w0;
        *(s16x8*)(C + q0 * CSTR + h * 16 + 8) = w1;
        if (h == 0) M[q0] = mm;
    }

    int nc = NC0, ph = 0;
#pragma unroll
    for (int s = 1; s <= STEPS; ++s) {
        const int nstr = (nc >= 16) ? (nc >> 4) : 1;
#pragma unroll
        for (int st = 0; st < nstr; ++st, ++ph) {
            LDS_WAIT();   // drain this wave's DS writes; compiler mem barrier
            int q = st * 16 + ql;
            bool valid = q < nc;
            s16x8 b = *(const s16x8*)(C + q * CSTR + kg * 8);
            f32x4 d0 = {0.f, 0.f, 0.f, 0.f};
            f32x4 d1 = {0.f, 0.f, 0.f, 0.f};
            d0 = __builtin_amdgcn_mfma_f32_16x16x32_bf16(a0, b, d0, 0, 0, 0);
            d1 = __builtin_amdgcn_mfma_f32_16x16x32_bf16(a1, b, d1, 0, 0, 0);
            float mq = M[q];
            float mpair = mq + __shfl_xor(mq, 1);   // m_L + m_R for pair
            int p = q >> 1;
            float4 e0 = pe0[ph], e1 = pe1[ph];
            // exp(em): depends only on prefetched registers, off the MFMA path
            float w0[4] = {__expf(e0.x), __expf(e0.y),
                           __expf(e0.z), __expf(e0.w)};
            float w1[4] = {__expf(e1.x), __expf(e1.y),
                           __expf(e1.z), __expf(e1.w)};
            float u0[4], u1[4];
#pragma unroll
            for (int r = 0; r < 4; ++r) {
                // sibling product: identical on both lanes of the pair
                u0[r] = d0[r] * __shfl_xor(d0[r], 1) * w0[r];
                u1[r] = d1[r] * __shfl_xor(d1[r], 1) * w1[r];
            }
            if (s == STEPS) {
                if (ql == 0) {                    // single parent row out
                    float4 o0 = {mpair + __logf(u0[0]), mpair + __logf(u0[1]),
                                 mpair + __logf(u0[2]), mpair + __logf(u0[3])};
                    float4 o1 = {mpair + __logf(u1[0]), mpair + __logf(u1[1]),
                                 mpair + __logf(u1[2]), mpair + __logf(u1[3])};
                    *(float4*)(outrow + kg * 4) = o0;
                    *(float4*)(outrow + 16 + kg * 4) = o1;
                }
            } else {
                // mu = max over the parent's 32 channels (per-ql reduce over
                // kg lanes only — invalid lanes never pollute valid ones)
                float m2 = fmaxf(
                    fmaxf(fmaxf(u0[0], u0[1]), fmaxf(u0[2], u0[3])),
                    fmaxf(fmaxf(u1[0], u1[1]), fmaxf(u1[2], u1[3])));
                m2 = fmaxf(m2, __shfl_xor(m2, 16));
                m2 = fmaxf(m2, __shfl_xor(m2, 32));
                // power-of-2 renorm: scale = 2^-ex exactly (no rcp, no log)
                unsigned mb = __builtin_bit_cast(unsigned, m2);
                int ex = (int)((mb >> 23) & 0xFFu) - 127;
                float scale = __builtin_bit_cast(float,
                                                 (unsigned)(127 - ex) << 23);
                if (valid && !(q & 1)) {
                    s16x4 z0, z1;
                    z0[0] = f2bf(u0[0] * scale); z0[1] = f2bf(u0[1] * scale);
                    z0[2] = f2bf(u0[2] * scale); z0[3] = f2bf(u0[3] * scale);
                    z1[0] = f2bf(u1[0] * scale); z1[1] = f2bf(u1[1] * scale);
                    z1[2] = f2bf(u1[2] * scale); z1[3] = f2bf(u1[3] * scale);
                    *(s16x4*)(C + p * CSTR + kg * 4) = z0;
                    *(s16x4*)(C + p * CSTR + 16 + kg * 4) = z1;
                    if (kg == 0) M[p] = fmaf((float)ex, LN2F, mpair);
                }
            }
        }
        nc >>= 1;
    }
}

// Fused kernel: 1024 blocks x 4 waves.
//  stage 1: wave sid reduces 32 leaf rows -> ws1[sid]; block flag f1[b].
//  stage 2: blocks 0..31, wave sid2=b*4+wv spins on its 8 producer blocks
//           (f1[b*32+wv*8 .. +8)), reduces ws1 -> ws2[sid2]; flag f2[b].
//  tail:    block 0, wave wv spins on f2[wv*8 .. +8), reduces ws2 -> R4;
//           barrier; wave 0 reduces R4 -> root. Waves 1-3 clear flags
//           (hidden under the root reduce).
__global__ __launch_bounds__(256) void treecrf_fused(
    const float* __restrict__ em, const float* __restrict__ trans,
    float* __restrict__ ws1, float* __restrict__ ws2,
    int* __restrict__ f1, int* __restrict__ f2,
    float* __restrict__ out_root, int n_leaves)
{
    __shared__ short C[4 * 32 * CSTR];
    __shared__ float M[4 * 32];
    __shared__ float R4[4 * 32];
    int t = threadIdx.x, lane = t & 63, wv = t >> 6;
    int b = blockIdx.x;
    int sid = b * 4 + wv;
    s16x8 a0, a1;
    load_afrag(trans, lane & 15, lane >> 4, &a0);
    load_afrag(trans, (lane & 15) + 16, lane >> 4, &a1);

    // ---- stage 1: leaves (width 131072) -> ws1 (width 4096)
    wave_reduce<32>(lane, em + (size_t)(n_leaves - 1) * 32 + (size_t)sid * 1024,
                    em, n_leaves, sid, a0, a1,
                    C + wv * 32 * CSTR, M + wv * 32, ws1 + (size_t)sid * 32);
    __syncthreads();               // drains all 4 waves' global stores (vmcnt)
    if (t == 0) { __threadfence(); atomicExch(&f1[b], DONE_MAGIC); }
    if (b >= 32) return;

    // ---- stage 2: ws1 (4096) -> ws2 (128); overlaps stage-1 stragglers
    spin_acquire(f1 + b * 32 + wv * 8, lane, 8);
    wave_reduce<32>(lane, ws1 + (size_t)sid * 1024, em, 4096, sid,
                    a0, a1, C + wv * 32 * CSTR, M + wv * 32,
                    ws2 + (size_t)sid * 32);
    __syncthreads();
    if (t == 0) { __threadfence(); atomicExch(&f2[b], DONE_MAGIC); }
    if (b != 0) return;

    // ---- tail: ws2 (128) -> R4 (4) -> root
    spin_acquire(f2 + wv * 8, lane, 8);
    wave_reduce<32>(lane, ws2 + (size_t)wv * 1024, em, 128, wv,
                    a0, a1, C + wv * 32 * CSTR, M + wv * 32, R4 + wv * 32);
    __syncthreads();               // cross-wave R4 handoff; f2[0..31] all seen
    if (wv == 0) {
        wave_reduce<4>(lane, R4, em, 4, 0, a0, a1, C, M, out_root);
    } else {
        // all consumers of f1/f2 are provably done; reset for next replay
        for (int i = t - 64; i < 1024; i += 192) f1[i] = 0;
        if (t - 64 < 32) f2[t - 64] = 0;
    }
}

extern "C" void kernel_launch(void* const* d_in, const int* in_sizes, int n_in,
                              void* d_out, int out_size, void* d_ws, size_t ws_size,
                              hipStream_t stream)
{
    const float* em = (const float*)d_in[0];
    const float* trans = (const float*)d_in[1];
    int n_nodes = in_sizes[0] / 32;          // 262143
    int n_leaves = (n_nodes + 1) / 2;        // 131072

    float* ws1 = (float*)d_ws;               // 4096 rows x 32 f32
    float* ws2 = ws1 + (size_t)4096 * 32;    // 128 rows x 32 f32
    int* f1 = (int*)(ws2 + (size_t)128 * 32);   // 1024 block flags
    int* f2 = f1 + 1024;                        // 32 block flags

    treecrf_fused<<<dim3(n_leaves / 128), dim3(256), 0, stream>>>(
        em, trans, ws1, ws2, f1, f2, (float*)d_out, n_leaves);
}

// Round 3
// 94.709 us; speedup vs baseline: 1.1636x; 1.1636x over previous
//
#include <hip/hip_runtime.h>

// TreeCRF inside pass, L=32 channels, perfect binary tree (heap layout).
// parent[i] = em[i] + LSE_j(T[i,j]+left[j]) + LSE_j(T[i,j]+right[j])
//
// R15 = back to the 2-launch structure (R13), linear-domain propagation +
// pow2 renorm kept, with the key change:
//   ILP x2: each wave reduces TWO independent 32-leaf subtrees, phase-
//   interleaved (wave_reduce2). The two dependency chains hide each other's
//   MFMA / transcendental / LDS latencies.
//   Em rows use a ONE-PHASE-LOOKAHEAD register prefetch (4 float4 in flight)
//   instead of R13's full 12-float4 array — R2 profiling showed VGPR_Count=68,
//   i.e. the compiler sank/spilled the big prefetch arrays, putting a
//   dependent global load inside every phase. __launch_bounds__(256,2) gives
//   the allocator a 256-VGPR budget so the lookahead stays in registers.
//
//  K1: 512 blocks x 4 waves, wave w reduces subtrees 2w,2w+1 -> ws1 (4096
//      rows). Block 0 zeroes the K2 ticket counter.
//  K2: 16 blocks x 4 waves reduce 4096 -> 128 (ws2); threadfence + ticket;
//      last block: waves 0,1 reduce 128 -> 4 (R4), wave 0 reduces 4 -> root.

typedef float f32x4 __attribute__((ext_vector_type(4)));
typedef short s16x8 __attribute__((ext_vector_type(8)));
typedef short s16x4 __attribute__((ext_vector_type(4)));

#define CSTR 40   // C row stride in shorts (80 B: 16B-aligned, <=2-way banks)
#define LDS_WAIT() __asm__ volatile("s_waitcnt lgkmcnt(0)" ::: "memory")
#define LN2F 0.69314718055994531f

__device__ __forceinline__ short f2bf(float f) {
    unsigned u = __builtin_bit_cast(unsigned, f);
    unsigned r = (u + 0x7fffu + ((u >> 16) & 1u)) >> 16;   // RNE to bf16
    return (short)r;
}

__device__ __forceinline__ float max4(float4 v) {
    return fmaxf(fmaxf(v.x, v.y), fmaxf(v.z, v.w));
}

__device__ __forceinline__ void load_afrag(const float* __restrict__ trans,
                                           int row, int kg, s16x8* a)
{
#pragma unroll
    for (int j = 0; j < 8; ++j)
        (*a)[j] = f2bf(__expf(trans[row * 32 + kg * 8 + j]));
}

// stage 0 for one tree: V = exp(x - rowmax) -> Cp, rowmax -> Mp.
__device__ __forceinline__ void stage0_tree(
    int q0, int h, float4 x0, float4 x1, float4 x2, float4 x3,
    short* Cp, float* Mp)
{
    float mm = fmaxf(fmaxf(max4(x0), max4(x1)), fmaxf(max4(x2), max4(x3)));
    mm = fmaxf(mm, __shfl_xor(mm, 32));           // combine the two halves
    s16x8 w0, w1;
    w0[0] = f2bf(__expf(x0.x - mm)); w0[1] = f2bf(__expf(x0.y - mm));
    w0[2] = f2bf(__expf(x0.z - mm)); w0[3] = f2bf(__expf(x0.w - mm));
    w0[4] = f2bf(__expf(x1.x - mm)); w0[5] = f2bf(__expf(x1.y - mm));
    w0[6] = f2bf(__expf(x1.z - mm)); w0[7] = f2bf(__expf(x1.w - mm));
    w1[0] = f2bf(__expf(x2.x - mm)); w1[1] = f2bf(__expf(x2.y - mm));
    w1[2] = f2bf(__expf(x2.z - mm)); w1[3] = f2bf(__expf(x2.w - mm));
    w1[4] = f2bf(__expf(x3.x - mm)); w1[5] = f2bf(__expf(x3.y - mm));
    w1[6] = f2bf(__expf(x3.z - mm)); w1[7] = f2bf(__expf(x3.w - mm));
    *(s16x8*)(Cp + q0 * CSTR + h * 16) = w0;
    *(s16x8*)(Cp + q0 * CSTR + h * 16 + 8) = w1;
    if (h == 0) Mp[q0] = mm;
}

// One wave reduces TWO independent 32-row subtrees (sidA, sidB) -> two f32
// output rows, phases interleaved for ILP. C must span 64 rows, M 64 floats.
// em node for (s, st): (inW>>s)-1 + sid*(32>>s) + ((st*16+ql)>>1).
__device__ __forceinline__ void wave_reduce2(
    int lane, const float* rowsA, const float* rowsB,
    const float* __restrict__ em, int inW, int sidA, int sidB,
    s16x8 a0, s16x8 a1, short* C, float* M, float* outA, float* outB)
{
    const int ql = lane & 15, kg = lane >> 4;
    const int q0 = lane & 31, h = lane >> 5;
    short* CB = C + 32 * CSTR;
    float* MB = M + 32;

    // stage-0 row loads first (8 dwordx4 in flight)
    const float4* srcA = (const float4*)(rowsA + q0 * 32 + h * 16);
    const float4* srcB = (const float4*)(rowsB + q0 * 32 + h * 16);
    float4 xA0 = srcA[0], xA1 = srcA[1], xA2 = srcA[2], xA3 = srcA[3];
    float4 xB0 = srcB[0], xB1 = srcB[1], xB2 = srcB[2], xB3 = srcB[3];

    // em rows for phase 0 (s=1, st=0) — one-phase lookahead registers
    float4 eA0, eA1, eB0, eB1;
    {
        int p = ql >> 1;
        size_t nA = (size_t)((inW >> 1) - 1) + (size_t)sidA * 16 + p;
        size_t nB = (size_t)((inW >> 1) - 1) + (size_t)sidB * 16 + p;
        eA0 = *(const float4*)(em + nA * 32 + kg * 4);
        eA1 = *(const float4*)(em + nA * 32 + 16 + kg * 4);
        eB0 = *(const float4*)(em + nB * 32 + kg * 4);
        eB1 = *(const float4*)(em + nB * 32 + 16 + kg * 4);
    }

    stage0_tree(q0, h, xA0, xA1, xA2, xA3, C, M);
    stage0_tree(q0, h, xB0, xB1, xB2, xB3, CB, MB);

    // phase schedule: (s, st) = (1,0) (1,1) (2,0) (3,0) (4,0) (5,0)
    constexpr int PS[6]  = {1, 1, 2, 3, 4, 5};
    constexpr int PST[6] = {0, 1, 0, 0, 0, 0};
    constexpr int PNC[6] = {32, 32, 16, 8, 4, 2};

#pragma unroll
    for (int ph = 0; ph < 6; ++ph) {
        const int s = PS[ph], st = PST[ph], nc = PNC[ph];
        // issue NEXT phase's em loads (independent; in flight over compute)
        float4 nA0, nA1, nB0, nB1;
        if (ph < 5) {
            const int s2 = PS[ph + 1], st2 = PST[ph + 1];
            int p2 = (st2 * 16 + ql) >> 1;
            size_t nA = (size_t)((inW >> s2) - 1)
                      + (size_t)sidA * (32 >> s2) + p2;
            size_t nB = (size_t)((inW >> s2) - 1)
                      + (size_t)sidB * (32 >> s2) + p2;
            nA0 = *(const float4*)(em + nA * 32 + kg * 4);
            nA1 = *(const float4*)(em + nA * 32 + 16 + kg * 4);
            nB0 = *(const float4*)(em + nB * 32 + kg * 4);
            nB1 = *(const float4*)(em + nB * 32 + 16 + kg * 4);
        }
        LDS_WAIT();   // drain this wave's DS writes; compiler mem barrier
        const int q = st * 16 + ql;
        const bool valid = q < nc;
        s16x8 bA = *(const s16x8*)(C + q * CSTR + kg * 8);
        s16x8 bB = *(const s16x8*)(CB + q * CSTR + kg * 8);
        float mqA = M[q], mqB = MB[q];
        f32x4 z = {0.f, 0.f, 0.f, 0.f};
        f32x4 dA0 = __builtin_amdgcn_mfma_f32_16x16x32_bf16(a0, bA, z, 0, 0, 0);
        f32x4 dA1 = __builtin_amdgcn_mfma_f32_16x16x32_bf16(a1, bA, z, 0, 0, 0);
        f32x4 dB0 = __builtin_amdgcn_mfma_f32_16x16x32_bf16(a0, bB, z, 0, 0, 0);
        f32x4 dB1 = __builtin_amdgcn_mfma_f32_16x16x32_bf16(a1, bB, z, 0, 0, 0);
        float mpA = mqA + __shfl_xor(mqA, 1);   // m_L + m_R for the pair
        float mpB = mqB + __shfl_xor(mqB, 1);
        // exp(em): depends only on already-loaded registers (off MFMA path)
        float wA0[4] = {__expf(eA0.x), __expf(eA0.y),
                        __expf(eA0.z), __expf(eA0.w)};
        float wA1[4] = {__expf(eA1.x), __expf(eA1.y),
                        __expf(eA1.z), __expf(eA1.w)};
        float wB0[4] = {__expf(eB0.x), __expf(eB0.y),
                        __expf(eB0.z), __expf(eB0.w)};
        float wB1[4] = {__expf(eB1.x), __expf(eB1.y),
                        __expf(eB1.z), __expf(eB1.w)};
        float uA0[4], uA1[4], uB0[4], uB1[4];
#pragma unroll
        for (int r = 0; r < 4; ++r) {
            uA0[r] = dA0[r] * __shfl_xor(dA0[r], 1) * wA0[r];
            uA1[r] = dA1[r] * __shfl_xor(dA1[r], 1) * wA1[r];
            uB0[r] = dB0[r] * __shfl_xor(dB0[r], 1) * wB0[r];
            uB1[r] = dB1[r] * __shfl_xor(dB1[r], 1) * wB1[r];
        }
        if (ph == 5) {
            if (ql == 0) {                        // single parent row out
                float4 oA0 = {mpA + __logf(uA0[0]), mpA + __logf(uA0[1]),
                              mpA + __logf(uA0[2]), mpA + __logf(uA0[3])};
                float4 oA1 = {mpA + __logf(uA1[0]), mpA + __logf(uA1[1]),
                              mpA + __logf(uA1[2]), mpA + __logf(uA1[3])};
                float4 oB0 = {mpB + __logf(uB0[0]), mpB + __logf(uB0[1]),
                              mpB + __logf(uB0[2]), mpB + __logf(uB0[3])};
                float4 oB1 = {mpB + __logf(uB1[0]), mpB + __logf(uB1[1]),
                              mpB + __logf(uB1[2]), mpB + __logf(uB1[3])};
                *(float4*)(outA + kg * 4) = oA0;
                *(float4*)(outA + 16 + kg * 4) = oA1;
                *(float4*)(outB + kg * 4) = oB0;
                *(float4*)(outB + 16 + kg * 4) = oB1;
            }
        } else {
            // mu = max over the parent's 32 channels (same-ql lanes only:
            // invalid-ql garbage never pollutes valid lanes)
            float m2A = fmaxf(
                fmaxf(fmaxf(uA0[0], uA0[1]), fmaxf(uA0[2], uA0[3])),
                fmaxf(fmaxf(uA1[0], uA1[1]), fmaxf(uA1[2], uA1[3])));
            m2A = fmaxf(m2A, __shfl_xor(m2A, 16));
            m2A = fmaxf(m2A, __shfl_xor(m2A, 32));
            float m2B = fmaxf(
                fmaxf(fmaxf(uB0[0], uB0[1]), fmaxf(uB0[2], uB0[3])),
                fmaxf(fmaxf(uB1[0], uB1[1]), fmaxf(uB1[2], uB1[3])));
            m2B = fmaxf(m2B, __shfl_xor(m2B, 16));
            m2B = fmaxf(m2B, __shfl_xor(m2B, 32));
            // power-of-2 renorm: scale = 2^-ex exactly (no rcp, no log)
            unsigned mbA = __builtin_bit_cast(unsigned, m2A);
            int exA = (int)((mbA >> 23) & 0xFFu) - 127;
            float scA = __builtin_bit_cast(float, (unsigned)(127 - exA) << 23);
            unsigned mbB = __builtin_bit_cast(unsigned, m2B);
            int exB = (int)((mbB >> 23) & 0xFFu) - 127;
            float scB = __builtin_bit_cast(float, (unsigned)(127 - exB) << 23);
            int p = q >> 1;
            if (valid && !(q & 1)) {
                s16x4 zA0, zA1, zB0, zB1;
                zA0[0] = f2bf(uA0[0] * scA); zA0[1] = f2bf(uA0[1] * scA);
                zA0[2] = f2bf(uA0[2] * scA); zA0[3] = f2bf(uA0[3] * scA);
                zA1[0] = f2bf(uA1[0] * scA); zA1[1] = f2bf(uA1[1] * scA);
                zA1[2] = f2bf(uA1[2] * scA); zA1[3] = f2bf(uA1[3] * scA);
                zB0[0] = f2bf(uB0[0] * scB); zB0[1] = f2bf(uB0[1] * scB);
                zB0[2] = f2bf(uB0[2] * scB); zB0[3] = f2bf(uB0[3] * scB);
                zB1[0] = f2bf(uB1[0] * scB); zB1[1] = f2bf(uB1[1] * scB);
                zB1[2] = f2bf(uB1[2] * scB); zB1[3] = f2bf(uB1[3] * scB);
                *(s16x4*)(C + p * CSTR + kg * 4) = zA0;
                *(s16x4*)(C + p * CSTR + 16 + kg * 4) = zA1;
                *(s16x4*)(CB + p * CSTR + kg * 4) = zB0;
                *(s16x4*)(CB + p * CSTR + 16 + kg * 4) = zB1;
                if (kg == 0) {
                    M[p]  = fmaf((float)exA, LN2F, mpA);
                    MB[p] = fmaf((float)exB, LN2F, mpB);
                }
            }
            eA0 = nA0; eA1 = nA1; eB0 = nB0; eB1 = nB1;
        }
    }
}

// Single-tree reducer, used only for the final 4 -> 1 (NC0 = 4).
template <int NC0>
__device__ __forceinline__ void wave_reduce(
    int lane, const float* rows, const float* __restrict__ em, int inW,
    int sid, s16x8 a0, s16x8 a1, short* C, float* M, float* outrow)
{
    constexpr int STEPS = 2, NPH = 2;
    const int ql = lane & 15, kg = lane >> 4;
    const int q0 = lane & 31, h = lane >> 5;

    float4 x0 = {0,0,0,0}, x1 = x0, x2 = x0, x3 = x0;
    if (q0 < NC0) {
        const float4* src = (const float4*)(rows + q0 * 32 + h * 16);
        x0 = src[0]; x1 = src[1]; x2 = src[2]; x3 = src[3];
    }
    float4 pe0[NPH], pe1[NPH];
#pragma unroll
    for (int s = 1; s <= STEPS; ++s) {
        int p = ql >> 1;
        size_t node = (size_t)((inW >> s) - 1) + (size_t)sid * (NC0 >> s) + p;
        pe0[s - 1] = *(const float4*)(em + node * 32 + kg * 4);
        pe1[s - 1] = *(const float4*)(em + node * 32 + 16 + kg * 4);
    }
    if (q0 < NC0) {
        float mm = fmaxf(fmaxf(max4(x0), max4(x1)),
                         fmaxf(max4(x2), max4(x3)));
        mm = fmaxf(mm, __shfl_xor(mm, 32));
        s16x8 w0, w1;
        w0[0] = f2bf(__expf(x0.x - mm)); w0[1] = f2bf(__expf(x0.y - mm));
        w0[2] = f2bf(__expf(x0.z - mm)); w0[3] = f2bf(__expf(x0.w - mm));
        w0[4] = f2bf(__expf(x1.x - mm)); w0[5] = f2bf(__expf(x1.y - mm));
        w0[6] = f2bf(__expf(x1.z - mm)); w0[7] = f2bf(__expf(x1.w - mm));
        w1[0] = f2bf(__expf(x2.x - mm)); w1[1] = f2bf(__expf(x2.y - mm));
        w1[2] = f2bf(__expf(x2.z - mm)); w1[3] = f2bf(__expf(x2.w - mm));
        w1[4] = f2bf(__expf(x3.x - mm)); w1[5] = f2bf(__expf(x3.y - mm));
        w1[6] = f2bf(__expf(x3.z - mm)); w1[7] = f2bf(__expf(x3.w - mm));
        *(s16x8*)(C + q0 * CSTR + h * 16) = w0;
        *(s16x8*)(C + q0 * CSTR + h * 16 + 8) = w1;
        if (h == 0) M[q0] = mm;
    }
    int nc = NC0;
#pragma unroll
    for (int s = 1; s <= STEPS; ++s) {
        LDS_WAIT();
        int q = ql;
        bool valid = q < nc;
        s16x8 b = *(const s16x8*)(C + q * CSTR + kg * 8);
        f32x4 zz = {0.f, 0.f, 0.f, 0.f};
        f32x4 d0 = __builtin_amdgcn_mfma_f32_16x16x32_bf16(a0, b, zz, 0, 0, 0);
        f32x4 d1 = __builtin_amdgcn_mfma_f32_16x16x32_bf16(a1, b, zz, 0, 0, 0);
        float mq = M[q];
        float mpair = mq + __shfl_xor(mq, 1);
        int p = q >> 1;
        float4 e0 = pe0[s - 1], e1 = pe1[s - 1];
        float w0[4] = {__expf(e0.x), __expf(e0.y), __expf(e0.z), __expf(e0.w)};
        float w1[4] = {__expf(e1.x), __expf(e1.y), __expf(e1.z), __expf(e1.w)};
        float u0[4], u1[4];
#pragma unroll
        for (int r = 0; r < 4; ++r) {
            u0[r] = d0[r] * __shfl_xor(d0[r], 1) * w0[r];
            u1[r] = d1[r] * __shfl_xor(d1[r], 1) * w1[r];
        }
        if (s == STEPS) {
            if (ql == 0) {
                float4 o0 = {mpair + __logf(u0[0]), mpair + __logf(u0[1]),
                             mpair + __logf(u0[2]), mpair + __logf(u0[3])};
                float4 o1 = {mpair + __logf(u1[0]), mpair + __logf(u1[1]),
                             mpair + __logf(u1[2]), mpair + __logf(u1[3])};
                *(float4*)(outrow + kg * 4) = o0;
                *(float4*)(outrow + 16 + kg * 4) = o1;
            }
        } else {
            float m2 = fmaxf(
                fmaxf(fmaxf(u0[0], u0[1]), fmaxf(u0[2], u0[3])),
                fmaxf(fmaxf(u1[0], u1[1]), fmaxf(u1[2], u1[3])));
            m2 = fmaxf(m2, __shfl_xor(m2, 16));
            m2 = fmaxf(m2, __shfl_xor(m2, 32));
            unsigned mb = __builtin_bit_cast(unsigned, m2);
            int ex = (int)((mb >> 23) & 0xFFu) - 127;
            float scale = __builtin_bit_cast(float, (unsigned)(127 - ex) << 23);
            if (valid && !(q & 1)) {
                s16x4 z0, z1;
                z0[0] = f2bf(u0[0] * scale); z0[1] = f2bf(u0[1] * scale);
                z0[2] = f2bf(u0[2] * scale); z0[3] = f2bf(u0[3] * scale);
                z1[0] = f2bf(u1[0] * scale); z1[1] = f2bf(u1[1] * scale);
                z1[2] = f2bf(u1[2] * scale); z1[3] = f2bf(u1[3] * scale);
                *(s16x4*)(C + p * CSTR + kg * 4) = z0;
                *(s16x4*)(C + p * CSTR + 16 + kg * 4) = z1;
                if (kg == 0) M[p] = fmaf((float)ex, LN2F, mpair);
            }
        }
        nc >>= 1;
    }
}

// K1: 512 blocks x 4 waves; wave w reduces subtrees 2w, 2w+1 -> ws1.
__global__ __launch_bounds__(256, 2) void treecrf_stage1(
    const float* __restrict__ rows_base, const float* __restrict__ em,
    const float* __restrict__ trans, float* __restrict__ out, int inW,
    int* __restrict__ counter)
{
    __shared__ short C[4 * 64 * CSTR];
    __shared__ float M[4 * 64];
    int t = threadIdx.x, lane = t & 63, wv = t >> 6;
    if (blockIdx.x == 0 && t == 0) *counter = 0;
    int w = blockIdx.x * 4 + wv;
    int sidA = 2 * w, sidB = 2 * w + 1;
    s16x8 a0, a1;
    load_afrag(trans, lane & 15, lane >> 4, &a0);
    load_afrag(trans, (lane & 15) + 16, lane >> 4, &a1);
    wave_reduce2(lane, rows_base + (size_t)sidA * 1024,
                 rows_base + (size_t)sidB * 1024, em, inW, sidA, sidB,
                 a0, a1, C + wv * 64 * CSTR, M + wv * 64,
                 out + (size_t)sidA * 32, out + (size_t)sidB * 32);
}

// K2: 16 blocks x 4 waves reduce 4096 -> 128 (ws2); ticket; last block runs
// 128 -> 4 (waves 0,1 into LDS R4) -> barrier -> 4 -> 1 (wave 0) -> root.
__global__ __launch_bounds__(256, 2) void treecrf_stage2(
    const float* __restrict__ ws1, float* __restrict__ ws2,
    const float* __restrict__ em, const float* __restrict__ trans,
    int* __restrict__ counter, float* __restrict__ out_root, int nbm1)
{
    __shared__ short C[4 * 64 * CSTR];
    __shared__ float M[4 * 64];
    __shared__ float R4[128];
    __shared__ int last_flag;
    int t = threadIdx.x, lane = t & 63, wv = t >> 6;
    int w = blockIdx.x * 4 + wv;
    s16x8 a0, a1;
    load_afrag(trans, lane & 15, lane >> 4, &a0);
    load_afrag(trans, (lane & 15) + 16, lane >> 4, &a1);
    wave_reduce2(lane, ws1 + (size_t)(2 * w) * 1024,
                 ws1 + (size_t)(2 * w + 1) * 1024, em, 4096, 2 * w, 2 * w + 1,
                 a0, a1, C + wv * 64 * CSTR, M + wv * 64,
                 ws2 + (size_t)(2 * w) * 32, ws2 + (size_t)(2 * w + 1) * 32);

    if (t == 0) {
        __threadfence();                   // release this block's ws2 rows
        last_flag = (atomicAdd(counter, 1) == nbm1);
    }
    __syncthreads();
    if (!last_flag) return;
    __threadfence();                       // acquire all ws2 rows

    if (wv < 2)
        wave_reduce2(lane, ws2 + (size_t)(2 * wv) * 1024,
                     ws2 + (size_t)(2 * wv + 1) * 1024, em, 128,
                     2 * wv, 2 * wv + 1,
                     a0, a1, C + wv * 64 * CSTR, M + wv * 64,
                     R4 + 2 * wv * 32, R4 + (2 * wv + 1) * 32);
    __syncthreads();                       // cross-wave R4 handoff
    if (wv == 0)
        wave_reduce<4>(lane, R4, em, 4, 0, a0, a1, C, M, out_root);
}

extern "C" void kernel_launch(void* const* d_in, const int* in_sizes, int n_in,
                              void* d_out, int out_size, void* d_ws, size_t ws_size,
                              hipStream_t stream)
{
    const float* em = (const float*)d_in[0];
    const float* trans = (const float*)d_in[1];
    int n_nodes = in_sizes[0] / 32;          // 262143
    int n_leaves = (n_nodes + 1) / 2;        // 131072

    float* ws1 = (float*)d_ws;               // 4096 rows x 32 f32
    float* ws2 = ws1 + (size_t)4096 * 32;    // 128 rows x 32 f32
    int* counter = (int*)(ws2 + (size_t)128 * 32);

    // K1: leaves (width 131072) -> width 4096. 2048 waves = 512 blocks.
    treecrf_stage1<<<dim3(n_leaves / 256), dim3(256), 0, stream>>>(
        em + (size_t)(n_leaves - 1) * 32, em, trans, ws1, n_leaves, counter);
    // K2: width 4096 -> root (last-block-done fuses the tail).
    treecrf_stage2<<<dim3(16), dim3(256), 0, stream>>>(
        ws1, ws2, em, trans, counter, (float*)d_out, 15);
}

// Round 4
// 91.849 us; speedup vs baseline: 1.1998x; 1.0311x over previous
//
#include <hip/hip_runtime.h>

// TreeCRF inside pass, L=32 channels, perfect binary tree (heap layout).
// parent[i] = em[i] + LSE_j(T[i,j]+left[j]) + LSE_j(T[i,j]+right[j])
//
// R16 = R13 verbatim (best measured: 91.53 us). Linear-domain propagation:
// each node carries V = exp(scores - m) (bf16, max-normalized) and scalar m.
//   u_i  = exp(em_i) * (E V_L)_i * (E V_R)_i      (f32, via MFMA + sibling shfl)
//   mu   = max_i u_i ;  V_p = u / mu ;  m_p = m_L + m_R + log(mu)
// Identity: scores_p[i] = m_p + log(V_p[i])  — exactly the old recurrence.
//
// Session accounting (R12-R15): dur_us is dominated by the harness's two
// ~43.5 us / 268 MB workspace re-poison fills (~87 us at 76-78% HBM peak);
// the treecrf kernels themselves are ~4-7 us (em is L3-resident, FETCH ~18MB).
// R14 (single-launch fusion) and R15 (ILP x2) both regressed; this structure
// is the measured optimum.
//
//  K1: 4096 waves reduce leaves -> width 4096 (block 0 zeroes the ticket).
//  K2: 32 blocks x 4 waves reduce 4096 -> 128; threadfence + atomicAdd ticket;
//      last block runs 128 -> 4 -> 1 to the root.

typedef float f32x4 __attribute__((ext_vector_type(4)));
typedef short s16x8 __attribute__((ext_vector_type(8)));
typedef short s16x4 __attribute__((ext_vector_type(4)));

#define CSTR 40   // C row stride in shorts (80 B: 16B-aligned, <=2-way banks)
#define LDS_WAIT() __asm__ volatile("s_waitcnt lgkmcnt(0)" ::: "memory")

__device__ __forceinline__ short f2bf(float f) {
    unsigned u = __builtin_bit_cast(unsigned, f);
    unsigned r = (u + 0x7fffu + ((u >> 16) & 1u)) >> 16;   // RNE to bf16
    return (short)r;
}

__device__ __forceinline__ float max4(float4 v) {
    return fmaxf(fmaxf(v.x, v.y), fmaxf(v.z, v.w));
}

__device__ __forceinline__ void load_afrag(const float* __restrict__ trans,
                                           int row, int kg, s16x8* a)
{
#pragma unroll
    for (int j = 0; j < 8; ++j)
        (*a)[j] = f2bf(__expf(trans[row * 32 + kg * 8 + j]));
}

// One wave reduces NC0 rows -> one f32 output row (log2(NC0) levels), fully
// autonomously. em node at step s: (inW>>s)-1 + sid*(NC0>>s) + p.
template <int NC0>
__device__ __forceinline__ void wave_reduce(
    int lane, const float* rows, const float* __restrict__ em, int inW,
    int sid, s16x8 a0, s16x8 a1, short* C, float* M, float* outrow)
{
    constexpr int STEPS = (NC0 == 32) ? 5 : 2;
    constexpr int NPH = (NC0 == 32) ? 6 : 2;
    const int ql = lane & 15, kg = lane >> 4;
    const int q0 = lane & 31, h = lane >> 5;

    // stage-0 row loads first
    float4 x0 = {0,0,0,0}, x1 = x0, x2 = x0, x3 = x0;
    if (q0 < NC0) {
        const float4* src = (const float4*)(rows + q0 * 32 + h * 16);
        x0 = src[0]; x1 = src[1]; x2 = src[2]; x3 = src[3];
    }

    // prefetch ALL em rows needed by the phases (independent, in-flight)
    float4 pe0[NPH], pe1[NPH];
    {
        int ph = 0;
#pragma unroll
        for (int s = 1; s <= STEPS; ++s) {
            const int nca = NC0 >> (s - 1);
            const int nstr = (nca >= 16) ? (nca >> 4) : 1;
#pragma unroll
            for (int st = 0; st < nstr; ++st, ++ph) {
                int p = (st * 16 + ql) >> 1;
                size_t node = (size_t)((inW >> s) - 1)
                            + (size_t)sid * (NC0 >> s) + p;
                pe0[ph] = *(const float4*)(em + node * 32 + kg * 4);
                pe1[ph] = *(const float4*)(em + node * 32 + 16 + kg * 4);
            }
        }
    }

    // stage 0: V = exp(x - rowmax) -> C, rowmax -> M. (True-max normalization
    // kept here: inputs are arbitrary log-domain scores.)
    if (q0 < NC0) {
        float mm = fmaxf(fmaxf(max4(x0), max4(x1)),
                         fmaxf(max4(x2), max4(x3)));
        mm = fmaxf(mm, __shfl_xor(mm, 32));       // combine the two halves
        s16x8 w0, w1;
        w0[0] = f2bf(__expf(x0.x - mm)); w0[1] = f2bf(__expf(x0.y - mm));
        w0[2] = f2bf(__expf(x0.z - mm)); w0[3] = f2bf(__expf(x0.w - mm));
        w0[4] = f2bf(__expf(x1.x - mm)); w0[5] = f2bf(__expf(x1.y - mm));
        w0[6] = f2bf(__expf(x1.z - mm)); w0[7] = f2bf(__expf(x1.w - mm));
        w1[0] = f2bf(__expf(x2.x - mm)); w1[1] = f2bf(__expf(x2.y - mm));
        w1[2] = f2bf(__expf(x2.z - mm)); w1[3] = f2bf(__expf(x2.w - mm));
        w1[4] = f2bf(__expf(x3.x - mm)); w1[5] = f2bf(__expf(x3.y - mm));
        w1[6] = f2bf(__expf(x3.z - mm)); w1[7] = f2bf(__expf(x3.w - mm));
        *(s16x8*)(C + q0 * CSTR + h * 16) = w0;
        *(s16x8*)(C + q0 * CSTR + h * 16 + 8) = w1;
        if (h == 0) M[q0] = mm;
    }

    int nc = NC0, ph = 0;
#pragma unroll
    for (int s = 1; s <= STEPS; ++s) {
        const int nstr = (nc >= 16) ? (nc >> 4) : 1;
#pragma unroll
        for (int st = 0; st < nstr; ++st, ++ph) {
            LDS_WAIT();   // drain this wave's DS writes; compiler mem barrier
            int q = st * 16 + ql;
            bool valid = q < nc;
            s16x8 b = *(const s16x8*)(C + q * CSTR + kg * 8);
            f32x4 d0 = {0.f, 0.f, 0.f, 0.f};
            f32x4 d1 = {0.f, 0.f, 0.f, 0.f};
            d0 = __builtin_amdgcn_mfma_f32_16x16x32_bf16(a0, b, d0, 0, 0, 0);
            d1 = __builtin_amdgcn_mfma_f32_16x16x32_bf16(a1, b, d1, 0, 0, 0);
            float mq = M[q];
            float mpair = mq + __shfl_xor(mq, 1);   // m_L + m_R for pair
            int p = q >> 1;
            float4 e0 = pe0[ph], e1 = pe1[ph];
            // exp(em): depends only on prefetched registers, off the MFMA path
            float w0[4] = {__expf(e0.x), __expf(e0.y),
                           __expf(e0.z), __expf(e0.w)};
            float w1[4] = {__expf(e1.x), __expf(e1.y),
                           __expf(e1.z), __expf(e1.w)};
            float u0[4], u1[4];
#pragma unroll
            for (int r = 0; r < 4; ++r) {
                // sibling product: identical on both lanes of the pair
                u0[r] = d0[r] * __shfl_xor(d0[r], 1) * w0[r];
                u1[r] = d1[r] * __shfl_xor(d1[r], 1) * w1[r];
            }
            if (s == STEPS) {
                if (ql == 0) {                    // single parent row out
                    float4 o0 = {mpair + __logf(u0[0]), mpair + __logf(u0[1]),
                                 mpair + __logf(u0[2]), mpair + __logf(u0[3])};
                    float4 o1 = {mpair + __logf(u1[0]), mpair + __logf(u1[1]),
                                 mpair + __logf(u1[2]), mpair + __logf(u1[3])};
                    *(float4*)(outrow + kg * 4) = o0;
                    *(float4*)(outrow + 16 + kg * 4) = o1;
                }
            } else {
                // mu = max over the parent's 32 channels (per-ql reduce over
                // kg lanes only — invalid lanes never pollute valid ones)
                float m2 = fmaxf(
                    fmaxf(fmaxf(u0[0], u0[1]), fmaxf(u0[2], u0[3])),
                    fmaxf(fmaxf(u1[0], u1[1]), fmaxf(u1[2], u1[3])));
                m2 = fmaxf(m2, __shfl_xor(m2, 16));
                m2 = fmaxf(m2, __shfl_xor(m2, 32));
                float inv = __fdividef(1.f, m2);   // v_rcp + mul, no trans chain
                if (valid && !(q & 1)) {
                    s16x4 z0, z1;
                    z0[0] = f2bf(u0[0] * inv); z0[1] = f2bf(u0[1] * inv);
                    z0[2] = f2bf(u0[2] * inv); z0[3] = f2bf(u0[3] * inv);
                    z1[0] = f2bf(u1[0] * inv); z1[1] = f2bf(u1[1] * inv);
                    z1[2] = f2bf(u1[2] * inv); z1[3] = f2bf(u1[3] * inv);
                    *(s16x4*)(C + p * CSTR + kg * 4) = z0;
                    *(s16x4*)(C + p * CSTR + 16 + kg * 4) = z1;
                    // off-path: log(mu) feeds only the scalar m accumulator
                    if (kg == 0) M[p] = mpair + __logf(m2);
                }
            }
        }
        nc >>= 1;
    }
}

// K1: 4 waves/block, wave wv reduces 32 leaf rows -> out[sid]. Block 0 also
// zeroes the K2 ticket counter (visible to K2 at kernel boundary).
__global__ __launch_bounds__(256) void treecrf_stage1(
    const float* __restrict__ rows_base, const float* __restrict__ em,
    const float* __restrict__ trans, float* __restrict__ out, int inW,
    int* __restrict__ counter)
{
    __shared__ short C[4 * 32 * CSTR];
    __shared__ float M[4 * 32];
    int t = threadIdx.x, lane = t & 63, wv = t >> 6;
    if (blockIdx.x == 0 && t == 0) *counter = 0;
    int sid = blockIdx.x * 4 + wv;
    s16x8 a0, a1;
    load_afrag(trans, lane & 15, lane >> 4, &a0);
    load_afrag(trans, (lane & 15) + 16, lane >> 4, &a1);
    wave_reduce<32>(lane, rows_base + (size_t)sid * 1024, em, inW, sid,
                    a0, a1, C + wv * 32 * CSTR, M + wv * 32,
                    out + (size_t)sid * 32);
}

// K2: 32 blocks x 4 waves reduce 4096 -> 128 (ws2); ticket; last block runs
// 128 -> 4 (4 waves into LDS) -> barrier -> 4 -> 1 (wave 0) -> root.
__global__ __launch_bounds__(256) void treecrf_stage2(
    const float* __restrict__ ws1, float* __restrict__ ws2,
    const float* __restrict__ em, const float* __restrict__ trans,
    int* __restrict__ counter, float* __restrict__ out_root, int nbm1)
{
    __shared__ short C[4 * 32 * CSTR];
    __shared__ float M[4 * 32];
    __shared__ float R4[4 * 32];
    __shared__ int last_flag;
    int t = threadIdx.x, lane = t & 63, wv = t >> 6;
    int sid = blockIdx.x * 4 + wv;
    s16x8 a0, a1;
    load_afrag(trans, lane & 15, lane >> 4, &a0);
    load_afrag(trans, (lane & 15) + 16, lane >> 4, &a1);
    wave_reduce<32>(lane, ws1 + (size_t)sid * 1024, em, 4096, sid,
                    a0, a1, C + wv * 32 * CSTR, M + wv * 32,
                    ws2 + (size_t)sid * 32);

    if (t == 0) {
        __threadfence();                   // release this block's ws2 rows
        last_flag = (atomicAdd(counter, 1) == nbm1);
    }
    __syncthreads();
    if (!last_flag) return;
    __threadfence();                       // acquire all ws2 rows

    wave_reduce<32>(lane, ws2 + (size_t)wv * 1024, em, 128, wv,
                    a0, a1, C + wv * 32 * CSTR, M + wv * 32, R4 + wv * 32);
    __syncthreads();                       // cross-wave R4 handoff
    if (wv == 0)
        wave_reduce<4>(lane, R4, em, 4, 0, a0, a1, C, M, out_root);
}

extern "C" void kernel_launch(void* const* d_in, const int* in_sizes, int n_in,
                              void* d_out, int out_size, void* d_ws, size_t ws_size,
                              hipStream_t stream)
{
    const float* em = (const float*)d_in[0];
    const float* trans = (const float*)d_in[1];
    int n_nodes = in_sizes[0] / 32;          // 262143
    int n_leaves = (n_nodes + 1) / 2;        // 131072

    float* ws1 = (float*)d_ws;               // 4096 rows
    float* ws2 = ws1 + (size_t)4096 * 32;    // 128 rows
    int* counter = (int*)(ws2 + (size_t)128 * 32);

    // K1: leaves (width 131072) -> width 4096. 4096 waves = 1024 blocks.
    treecrf_stage1<<<dim3(n_leaves / 128), dim3(256), 0, stream>>>(
        em + (size_t)(n_leaves - 1) * 32, em, trans, ws1, n_leaves, counter);
    // K2: width 4096 -> root (last-block-done fuses the tail).
    treecrf_stage2<<<dim3(32), dim3(256), 0, stream>>>(
        ws1, ws2, em, trans, counter, (float*)d_out, 31);
}